// Round 2
// baseline (4516.457 us; speedup 1.0000x reference)
//
#include <hip/hip_runtime.h>
#include <hip/hip_bf16.h>
#include <cstddef>

#define NNODE  20000
#define NEDGE  240000
#define NGRAPH 200
#define DIN    118
#define HD     256
#define NBASIS 10
#define RHID   100
#define NLAYER 3
#define NSH    9
#define SHPAD  12           // sh row stride (padded for float4 loads)
#define KTP    (NSH * HD)   // 2304

__device__ __forceinline__ float gelu_tanh(float v) {
  float v3 = v * v * v;
  return 0.5f * v * (1.f + tanhf(0.7978845608028654f * (v + 0.044715f * v3)));
}

// ---------------- edge geometry: sh[E,12] (9 used), emb[E,10] ----------------
__global__ void edge_geom_kernel(const float* __restrict__ pos,
                                 const float* __restrict__ shift,
                                 const float* __restrict__ lat,
                                 const int* __restrict__ ei,
                                 const int* __restrict__ batch,
                                 float* __restrict__ sh,
                                 float* __restrict__ emb)
{
  int e = blockIdx.x * 256 + threadIdx.x;
  if (e >= NEDGE) return;
  int src = ei[e];
  int dst = ei[NEDGE + e];
  int b = batch[src];
  const float* L = lat + (size_t)b * 9;
  float s0 = shift[e * 3 + 0], s1 = shift[e * 3 + 1], s2 = shift[e * 3 + 2];
  float ev[3];
#pragma unroll
  for (int j = 0; j < 3; ++j)
    ev[j] = pos[dst * 3 + j] - pos[src * 3 + j] + s0 * L[j] + s1 * L[3 + j] + s2 * L[6 + j];
  float len = sqrtf(ev[0] * ev[0] + ev[1] * ev[1] + ev[2] * ev[2]);
  float inv = 1.f / (len + 1e-12f);
  float x = ev[0] * inv, y = ev[1] * inv, z = ev[2] * inv;
  const float c1 = 1.7320508075688772f;   // sqrt(3)
  const float c2 = 3.872983346207417f;    // sqrt(15)
  float* she = sh + (size_t)e * SHPAD;
  she[0] = 1.f;
  she[1] = c1 * x;
  she[2] = c1 * y;
  she[3] = c1 * z;
  she[4] = c2 * x * y;
  she[5] = c2 * y * z;
  she[6] = 1.1180339887498949f * (3.f * z * z - 1.f);  // sqrt(5)/2
  she[7] = c2 * x * z;
  she[8] = 1.9364916731037085f * (x * x - y * y);      // sqrt(15)/2
  she[9] = 0.f; she[10] = 0.f; she[11] = 0.f;
  const float step = 5.f / 11.f;
  const float sq = 3.1622776601683795f;   // sqrt(10)
  float* eme = emb + (size_t)e * NBASIS;
#pragma unroll
  for (int k = 0; k < NBASIS; ++k) {
    float d = (len - (float)(k + 1) * step) / step;
    eme[k] = (d > -1.f && d < 1.f) ? cosf(1.5707963267948966f * d) * sq : 0.f;
  }
}

// ---------------- CSR build ----------------
__global__ void deg_hist_kernel(const int* __restrict__ ei, int* __restrict__ deg)
{
  int e = blockIdx.x * 256 + threadIdx.x;
  if (e >= NEDGE) return;
  atomicAdd(&deg[ei[NEDGE + e]], 1);
}

__global__ void scan_kernel(const int* __restrict__ deg, int* __restrict__ rowptr)
{
  __shared__ int part[256];
  int t = threadIdx.x;
  const int chunk = (NNODE + 255) / 256;
  int start = t * chunk;
  int end = min(start + chunk, NNODE);
  int s = 0;
  for (int i = start; i < end; ++i) s += deg[i];
  part[t] = s;
  __syncthreads();
  for (int off = 1; off < 256; off <<= 1) {
    int v = (t >= off) ? part[t - off] : 0;
    __syncthreads();
    part[t] += v;
    __syncthreads();
  }
  int run = (t == 0) ? 0 : part[t - 1];
  for (int i = start; i < end; ++i) { rowptr[i] = run; run += deg[i]; }
  if (t == 255) rowptr[NNODE] = run;
}

__global__ void fill_kernel(const int* __restrict__ ei,
                            const int* __restrict__ rowptr,
                            int* __restrict__ cursor,
                            int* __restrict__ eids)
{
  int e = blockIdx.x * 256 + threadIdx.x;
  if (e >= NEDGE) return;
  int dst = ei[NEDGE + e];
  int p = atomicAdd(&cursor[dst], 1);
  eids[rowptr[dst] + p] = e;
}

// ---------------- Wcomb = inv_sqrt_deg * Wtp_flat[l] @ Wself[l] ----------------
__global__ void wcomb_kernel(const float* __restrict__ Wtp_l,
                             const float* __restrict__ Wself_l,
                             float* __restrict__ Wcomb)
{
  int p = blockIdx.x;       // 0..2303
  int j = threadIdx.x;      // 0..255
  const float* wrow = Wtp_l + (size_t)p * HD;
  float s = 0.f;
  for (int m = 0; m < HD; ++m) s += wrow[m] * Wself_l[m * HD + j];
  Wcomb[(size_t)p * HD + j] = s * 0.28867513459481287f;  // 1/sqrt(12)
}

// ---------------- hs[e,c] = h[src_e,c] * (silu(emb@r1+b1)@r2)[e,c], bf16 out ----
#define EPB 64
__global__ __launch_bounds__(256) void hs_kernel(
    const int* __restrict__ ei, const float* __restrict__ emb,
    const float* __restrict__ h,
    const float* __restrict__ r1l, const float* __restrict__ b1l,
    const float* __restrict__ r2l, __hip_bfloat16* __restrict__ hs)
{
  __shared__ float rhT[RHID][EPB];     // transposed rh: [k][e]
  __shared__ float r2s[RHID][64];      // r2 col-block: [k][c]
  __shared__ float embs[EPB][NBASIS];
  __shared__ int   srcs[EPB];
  int t = threadIdx.x;
  int e0 = blockIdx.x * EPB;

  for (int idx = t; idx < EPB * NBASIS; idx += 256) {
    int e = idx / NBASIS, j = idx % NBASIS;
    embs[e][j] = emb[(size_t)(e0 + e) * NBASIS + j];
  }
  if (t < EPB) srcs[t] = ei[e0 + t];
  __syncthreads();

  // phase 1: rh = silu(emb @ r1 + b1), k distributed over t>>6 (wave-uniform)
  {
    int e = t & 63;
    int kbase = t >> 6;   // 0..3
#pragma unroll
    for (int i = 0; i < 25; ++i) {
      int k = i * 4 + kbase;
      float s = b1l[k];
#pragma unroll
      for (int j = 0; j < NBASIS; ++j) s += embs[e][j] * r1l[j * RHID + k];
      rhT[k][e] = s / (1.f + expf(-s));
    }
  }
  __syncthreads();

  int tx = t & 15, ty = t >> 4;   // thread computes 4 edges (ty*4+i) x 4 cols (tx*4+j)
  for (int cb = 0; cb < 4; ++cb) {
    for (int idx = t; idx < RHID * 64; idx += 256) {
      int k = idx >> 6, c = idx & 63;
      r2s[k][c] = r2l[(size_t)k * HD + cb * 64 + c];
    }
    __syncthreads();
    float acc[4][4];
#pragma unroll
    for (int i = 0; i < 4; ++i)
#pragma unroll
      for (int j = 0; j < 4; ++j) acc[i][j] = 0.f;
    for (int k = 0; k < RHID; ++k) {
      float4 av = *(const float4*)&rhT[k][ty * 4];
      float4 bv = *(const float4*)&r2s[k][tx * 4];
      float a[4] = {av.x, av.y, av.z, av.w};
      float b[4] = {bv.x, bv.y, bv.z, bv.w};
#pragma unroll
      for (int i = 0; i < 4; ++i)
#pragma unroll
        for (int j = 0; j < 4; ++j) acc[i][j] += a[i] * b[j];
    }
    // epilogue: multiply by gathered h[src] and store bf16
#pragma unroll
    for (int i = 0; i < 4; ++i) {
      int e = ty * 4 + i;
      int src = srcs[e];
      float4 hv = *(const float4*)(h + (size_t)src * HD + cb * 64 + tx * 4);
      __hip_bfloat16* o = hs + (size_t)(e0 + e) * HD + cb * 64 + tx * 4;
      __hip_bfloat162* o2 = (__hip_bfloat162*)o;
      o2[0] = __halves2bfloat162(__float2bfloat16(acc[i][0] * hv.x),
                                 __float2bfloat16(acc[i][1] * hv.y));
      o2[1] = __halves2bfloat162(__float2bfloat16(acc[i][2] * hv.z),
                                 __float2bfloat16(acc[i][3] * hv.w));
    }
    __syncthreads();
  }
}

// ---------------- gather: T[n, a*256+c] = sum_{e->n} sh[e,a]*hs[e,c] ----------
#define NPB2 5
__global__ __launch_bounds__(256) void gather_T2_kernel(
    const int* __restrict__ rowptr, const int* __restrict__ eids,
    const __hip_bfloat16* __restrict__ hs, const float* __restrict__ sh,
    float* __restrict__ T)
{
  int c = threadIdx.x;
  int n0 = blockIdx.x * NPB2;
  for (int n = n0; n < n0 + NPB2; ++n) {
    int beg = rowptr[n], end = rowptr[n + 1];
    float acc[NSH];
#pragma unroll
    for (int a = 0; a < NSH; ++a) acc[a] = 0.f;
    for (int j = beg; j < end; ++j) {
      int e = eids[j];
      const float* she = sh + (size_t)e * SHPAD;
      float4 sA = *(const float4*)she;
      float4 sB = *(const float4*)(she + 4);
      float  s8 = she[8];
      float hv = __bfloat162float(hs[(size_t)e * HD + c]);
      acc[0] += sA.x * hv; acc[1] += sA.y * hv; acc[2] += sA.z * hv;
      acc[3] += sA.w * hv; acc[4] += sB.x * hv; acc[5] += sB.y * hv;
      acc[6] += sB.z * hv; acc[7] += sB.w * hv; acc[8] += s8 * hv;
    }
    float* Tn = T + (size_t)n * KTP + c;
#pragma unroll
    for (int a = 0; a < NSH; ++a) Tn[a * HD] = acc[a];
  }
}

// ---------------- fallback gather (old path, if ws too small) ----------------
#define NPB 25
__global__ __launch_bounds__(256) void gather_T_kernel(
    const int* __restrict__ rowptr, const int* __restrict__ eids,
    const int* __restrict__ ei, const float* __restrict__ sh,
    const float* __restrict__ emb, const float* __restrict__ h,
    const float* __restrict__ r1l, const float* __restrict__ b1l,
    const float* __restrict__ r2l, float* __restrict__ T)
{
  int c = threadIdx.x;
  float r2c[RHID];
#pragma unroll
  for (int k = 0; k < RHID; ++k) r2c[k] = r2l[k * HD + c];
  __shared__ float emb_s[2][NBASIS];
  __shared__ float sh_s[2][NSH];
  __shared__ float rh_s[2][RHID];
  int n0 = blockIdx.x * NPB;
  for (int n = n0; n < n0 + NPB; ++n) {
    int beg = rowptr[n], end = rowptr[n + 1];
    float acc[NSH];
#pragma unroll
    for (int a = 0; a < NSH; ++a) acc[a] = 0.f;
    int buf = 0;
    for (int j = beg; j < end; ++j, buf ^= 1) {
      int e = eids[j];
      int src = ei[e];
      if (c < NBASIS) emb_s[buf][c] = emb[(size_t)e * NBASIS + c];
      else if (c < NBASIS + NSH) sh_s[buf][c - NBASIS] = sh[(size_t)e * SHPAD + (c - NBASIS)];
      __syncthreads();
      if (c < RHID) {
        float hsv = b1l[c];
#pragma unroll
        for (int k = 0; k < NBASIS; ++k) hsv += emb_s[buf][k] * r1l[k * RHID + c];
        rh_s[buf][c] = hsv / (1.f + expf(-hsv));
      }
      __syncthreads();
      float radial = 0.f;
#pragma unroll
      for (int k = 0; k < RHID; ++k) radial += rh_s[buf][k] * r2c[k];
      float hv = h[(size_t)src * HD + c] * radial;
#pragma unroll
      for (int a = 0; a < NSH; ++a) acc[a] += sh_s[buf][a] * hv;
    }
    float* Tn = T + (size_t)n * KTP + c;
#pragma unroll
    for (int a = 0; a < NSH; ++a) Tn[a * HD] = acc[a];
  }
}

// ---------------- fused GEMM: C = act(A1@B1 + A2@B2), N fixed = 256 ----------------
#define BM 64
#define BN 64
#define BK 16
__global__ __launch_bounds__(256) void gemm_fused_kernel(
    const float* __restrict__ A1, const float* __restrict__ B1, int K1,
    const float* __restrict__ A2, const float* __restrict__ B2, int K2,
    float* __restrict__ C, int M, int act)
{
  __shared__ float As[BK][BM];
  __shared__ float Bs[BK][BN];
  int tid = threadIdx.x;
  int tx = tid & 15, ty = tid >> 4;
  int row0 = blockIdx.x * BM;
  int col0 = blockIdx.y * BN;
  float acc[4][4];
#pragma unroll
  for (int i = 0; i < 4; ++i)
#pragma unroll
    for (int j = 0; j < 4; ++j) acc[i][j] = 0.f;

  for (int pass = 0; pass < 2; ++pass) {
    const float* A = pass ? A2 : A1;
    const float* B = pass ? B2 : B1;
    int K = pass ? K2 : K1;
    if (A == nullptr || K <= 0) continue;
    for (int k0 = 0; k0 < K; k0 += BK) {
      {
        int r = tid >> 2;
        int kq = (tid & 3) * 4;
        int gr = row0 + r;
#pragma unroll
        for (int j = 0; j < 4; ++j) {
          int gk = k0 + kq + j;
          As[kq + j][r] = (gr < M && gk < K) ? A[(size_t)gr * K + gk] : 0.f;
        }
      }
      {
#pragma unroll
        for (int t = 0; t < 4; ++t) {
          int idx = tid + t * 256;
          int kk = idx >> 6, nn = idx & 63;
          int gk = k0 + kk;
          Bs[kk][nn] = (gk < K) ? B[(size_t)gk * HD + col0 + nn] : 0.f;
        }
      }
      __syncthreads();
#pragma unroll
      for (int kk = 0; kk < BK; ++kk) {
        float a[4], b[4];
#pragma unroll
        for (int i = 0; i < 4; ++i) a[i] = As[kk][ty * 4 + i];
#pragma unroll
        for (int j = 0; j < 4; ++j) b[j] = Bs[kk][tx * 4 + j];
#pragma unroll
        for (int i = 0; i < 4; ++i)
#pragma unroll
          for (int j = 0; j < 4; ++j) acc[i][j] += a[i] * b[j];
      }
      __syncthreads();
    }
  }
#pragma unroll
  for (int i = 0; i < 4; ++i) {
    int row = row0 + ty * 4 + i;
    if (row >= M) continue;
#pragma unroll
    for (int j = 0; j < 4; ++j) {
      float v = acc[i][j];
      if (act == 1) v = gelu_tanh(v);
      C[(size_t)row * HD + col0 + tx * 4 + j] = v;
    }
  }
}

// ---------------- node_out + graph sums ----------------
__global__ void node_out_kernel(const float* __restrict__ h,
                                const float* __restrict__ Wout,
                                const int* __restrict__ batch,
                                float* __restrict__ sums,
                                float* __restrict__ cnts)
{
  int n = blockIdx.x * 4 + (threadIdx.x >> 6);
  int lane = threadIdx.x & 63;
  if (n >= NNODE) return;
  float s = 0.f;
#pragma unroll
  for (int t = 0; t < 4; ++t) {
    int c = lane + t * 64;
    s += h[(size_t)n * HD + c] * Wout[c];
  }
#pragma unroll
  for (int off = 32; off > 0; off >>= 1) s += __shfl_down(s, off);
  if (lane == 0) {
    int g = batch[n];
    atomicAdd(&sums[g], s);
    atomicAdd(&cnts[g], 1.f);
  }
}

__global__ void finalize_kernel(const float* __restrict__ sums,
                                const float* __restrict__ cnts,
                                float* __restrict__ out)
{
  int g = threadIdx.x;
  if (g < NGRAPH) out[g] = sums[g] / fmaxf(cnts[g], 1.f);
}

// ---------------- host launch ----------------
extern "C" void kernel_launch(void* const* d_in, const int* in_sizes, int n_in,
                              void* d_out, int out_size, void* d_ws, size_t ws_size,
                              hipStream_t stream)
{
  (void)in_sizes; (void)n_in; (void)out_size;
  const float* x     = (const float*)d_in[0];
  const float* pos   = (const float*)d_in[1];
  const float* shift = (const float*)d_in[2];
  const float* lat   = (const float*)d_in[3];
  const float* Wemb  = (const float*)d_in[4];
  const float* r1    = (const float*)d_in[5];
  const float* b1    = (const float*)d_in[6];
  const float* r2    = (const float*)d_in[7];
  const float* Wtp   = (const float*)d_in[8];
  const float* Wself = (const float*)d_in[9];
  const float* Wskip = (const float*)d_in[10];
  const float* Wout  = (const float*)d_in[11];
  const int*   eidx  = (const int*)d_in[12];
  const int*   batch = (const int*)d_in[13];
  float* out = (float*)d_out;

  char* ws = (char*)d_ws;
  size_t off = 0;
  auto alloc = [&](size_t bytes) -> char* {
    char* p = ws + off;
    off += (bytes + 255) & ~(size_t)255;
    return p;
  };
  float* sh    = (float*)alloc((size_t)NEDGE * SHPAD * 4);
  float* emb   = (float*)alloc((size_t)NEDGE * NBASIS * 4);
  float* hA    = (float*)alloc((size_t)NNODE * HD * 4);
  float* hB    = (float*)alloc((size_t)NNODE * HD * 4);
  float* T     = (float*)alloc((size_t)NNODE * KTP * 4);
  float* Wcomb = (float*)alloc((size_t)KTP * HD * 4);
  int*   rowptr = (int*)alloc((size_t)(NNODE + 1) * 4);
  int*   deg    = (int*)alloc((size_t)NNODE * 4);
  int*   cursor = (int*)alloc((size_t)NNODE * 4);
  int*   eids   = (int*)alloc((size_t)NEDGE * 4);
  float* sums   = (float*)alloc((size_t)NGRAPH * 4);
  float* cnts   = (float*)alloc((size_t)NGRAPH * 4);
  size_t base_off = off;
  __hip_bfloat16* hs = (__hip_bfloat16*)alloc((size_t)NEDGE * HD * 2);
  bool fast = (off <= ws_size);
  if (base_off > ws_size) return;  // can't run at all

  hipMemsetAsync(deg, 0, (size_t)NNODE * 4, stream);
  hipMemsetAsync(cursor, 0, (size_t)NNODE * 4, stream);
  hipMemsetAsync(sums, 0, (size_t)NGRAPH * 4, stream);
  hipMemsetAsync(cnts, 0, (size_t)NGRAPH * 4, stream);

  const int EB = (NEDGE + 255) / 256;
  edge_geom_kernel<<<EB, 256, 0, stream>>>(pos, shift, lat, eidx, batch, sh, emb);
  deg_hist_kernel<<<EB, 256, 0, stream>>>(eidx, deg);
  scan_kernel<<<1, 256, 0, stream>>>(deg, rowptr);
  fill_kernel<<<EB, 256, 0, stream>>>(eidx, rowptr, cursor, eids);

  // h = x @ W_embed
  dim3 ggrid((NNODE + BM - 1) / BM, HD / BN);
  gemm_fused_kernel<<<ggrid, 256, 0, stream>>>(x, Wemb, DIN, nullptr, nullptr, 0,
                                               hA, NNODE, 0);

  float* hcur = hA;
  float* hnxt = hB;
  for (int l = 0; l < NLAYER; ++l) {
    const float* r1l = r1 + (size_t)l * NBASIS * RHID;
    const float* b1l = b1 + (size_t)l * RHID;
    const float* r2l = r2 + (size_t)l * RHID * HD;
    const float* Wtp_l = Wtp + (size_t)l * NSH * HD * HD;
    const float* Wself_l = Wself + (size_t)l * HD * HD;
    const float* Wskip_l = Wskip + (size_t)l * HD * HD;

    wcomb_kernel<<<KTP, 256, 0, stream>>>(Wtp_l, Wself_l, Wcomb);
    if (fast) {
      hs_kernel<<<NEDGE / EPB, 256, 0, stream>>>(eidx, emb, hcur, r1l, b1l, r2l, hs);
      gather_T2_kernel<<<NNODE / NPB2, 256, 0, stream>>>(rowptr, eids, hs, sh, T);
    } else {
      gather_T_kernel<<<NNODE / NPB, 256, 0, stream>>>(rowptr, eids, eidx, sh, emb,
                                                       hcur, r1l, b1l, r2l, T);
    }
    gemm_fused_kernel<<<ggrid, 256, 0, stream>>>(T, Wcomb, KTP, hcur, Wskip_l, HD,
                                                 hnxt, NNODE, 1);
    float* tmp = hcur; hcur = hnxt; hnxt = tmp;
  }

  node_out_kernel<<<NNODE / 4, 256, 0, stream>>>(hcur, Wout, batch, sums, cnts);
  finalize_kernel<<<1, 256, 0, stream>>>(sums, cnts, out);
}

// Round 3
// 1581.143 us; speedup vs baseline: 2.8565x; 2.8565x over previous
//
#include <hip/hip_runtime.h>
#include <hip/hip_bf16.h>
#include <cstddef>
#include <cstdint>

#define NNODE  20000
#define MPAD   20096        // 157*128 padding for GEMM row tiles
#define NEDGE  240000
#define NGRAPH 200
#define DIN    118
#define HD     256
#define NBASIS 10
#define RHID   100
#define NLAYER 3
#define NSH    9
#define SHSTR  16           // sh row stride in f16 elements (32 B)
#define KTP    (NSH * HD)   // 2304
#define KTOT   (KTP + HD)   // 2560

typedef _Float16 f16;
typedef _Float16 f16x4 __attribute__((ext_vector_type(4)));
typedef _Float16 f16x8 __attribute__((ext_vector_type(8)));
typedef float    f32x4 __attribute__((ext_vector_type(4)));

__device__ __forceinline__ float gelu_tanh(float v) {
  float v3 = v * v * v;
  return 0.5f * v * (1.f + tanhf(0.7978845608028654f * (v + 0.044715f * v3)));
}

// ---------------- edge geometry: sh[E,16] f16 (9 used), lens[E] ----------------
__global__ void edge_geom_kernel(const float* __restrict__ pos,
                                 const float* __restrict__ shift,
                                 const float* __restrict__ lat,
                                 const int* __restrict__ ei,
                                 const int* __restrict__ batch,
                                 f16* __restrict__ sh,
                                 float* __restrict__ lens)
{
  int e = blockIdx.x * 256 + threadIdx.x;
  if (e >= NEDGE) return;
  int src = ei[e];
  int dst = ei[NEDGE + e];
  int b = batch[src];
  const float* L = lat + (size_t)b * 9;
  float s0 = shift[e * 3 + 0], s1 = shift[e * 3 + 1], s2 = shift[e * 3 + 2];
  float ev[3];
#pragma unroll
  for (int j = 0; j < 3; ++j)
    ev[j] = pos[dst * 3 + j] - pos[src * 3 + j] + s0 * L[j] + s1 * L[3 + j] + s2 * L[6 + j];
  float len = sqrtf(ev[0] * ev[0] + ev[1] * ev[1] + ev[2] * ev[2]);
  float inv = 1.f / (len + 1e-12f);
  float x = ev[0] * inv, y = ev[1] * inv, z = ev[2] * inv;
  const float c1 = 1.7320508075688772f;   // sqrt(3)
  const float c2 = 3.872983346207417f;    // sqrt(15)
  f16* she = sh + (size_t)e * SHSTR;
  she[0] = (f16)1.f;
  she[1] = (f16)(c1 * x);
  she[2] = (f16)(c1 * y);
  she[3] = (f16)(c1 * z);
  she[4] = (f16)(c2 * x * y);
  she[5] = (f16)(c2 * y * z);
  she[6] = (f16)(1.1180339887498949f * (3.f * z * z - 1.f));  // sqrt(5)/2
  she[7] = (f16)(c2 * x * z);
  she[8] = (f16)(1.9364916731037085f * (x * x - y * y));      // sqrt(15)/2
  lens[e] = len;
}

// ---------------- CSR build ----------------
__global__ void deg_hist_kernel(const int* __restrict__ ei, int* __restrict__ deg)
{
  int e = blockIdx.x * 256 + threadIdx.x;
  if (e >= NEDGE) return;
  atomicAdd(&deg[ei[NEDGE + e]], 1);
}

__global__ void scan_kernel(const int* __restrict__ deg, int* __restrict__ rowptr)
{
  __shared__ int part[256];
  int t = threadIdx.x;
  const int chunk = (NNODE + 255) / 256;
  int start = t * chunk;
  int end = min(start + chunk, NNODE);
  int s = 0;
  for (int i = start; i < end; ++i) s += deg[i];
  part[t] = s;
  __syncthreads();
  for (int off = 1; off < 256; off <<= 1) {
    int v = (t >= off) ? part[t - off] : 0;
    __syncthreads();
    part[t] += v;
    __syncthreads();
  }
  int run = (t == 0) ? 0 : part[t - 1];
  for (int i = start; i < end; ++i) { rowptr[i] = run; run += deg[i]; }
  if (t == 255) rowptr[NNODE] = run;
}

__global__ void fill_kernel(const int* __restrict__ ei,
                            const int* __restrict__ rowptr,
                            int* __restrict__ cursor,
                            int* __restrict__ eids)
{
  int e = blockIdx.x * 256 + threadIdx.x;
  if (e >= NEDGE) return;
  int dst = ei[NEDGE + e];
  int p = atomicAdd(&cursor[dst], 1);
  eids[rowptr[dst] + p] = e;
}

// ------- Bcat[n][k] f16 (n-major): k<2304: (Wtp_flat@Wself)*inv_sqrt_deg ; else Wskip -------
__global__ void wcat_kernel(const float* __restrict__ Wtp_l,
                            const float* __restrict__ Wself_l,
                            const float* __restrict__ Wskip_l,
                            f16* __restrict__ Bcat)
{
  int p = blockIdx.x;       // 0..2559 (k index)
  int j = threadIdx.x;      // 0..255  (n index)
  float s;
  if (p < KTP) {
    const float* wrow = Wtp_l + (size_t)p * HD;
    s = 0.f;
    for (int m = 0; m < HD; ++m) s += wrow[m] * Wself_l[m * HD + j];
    s *= 0.28867513459481287f;  // 1/sqrt(12)
  } else {
    s = Wskip_l[(size_t)(p - KTP) * HD + j];
  }
  Bcat[(size_t)j * KTOT + p] = (f16)s;
}

// ---------------- hs[e,c] = h[src_e,c] * (silu(emb@r1+b1)@r2)[e,c], f16 ----
#define EPB 64
__global__ __launch_bounds__(256) void hs_kernel(
    const int* __restrict__ ei, const float* __restrict__ lens,
    const f16* __restrict__ h,
    const float* __restrict__ r1l, const float* __restrict__ b1l,
    const float* __restrict__ r2l, f16* __restrict__ hs)
{
  __shared__ float rhT[RHID][EPB];     // transposed rh: [k][e]
  __shared__ float r2s[RHID][64];      // r2 col-block: [k][c]
  __shared__ float embs[EPB][NBASIS];
  __shared__ int   srcs[EPB];
  __shared__ float lens_s[EPB];
  int t = threadIdx.x;
  int e0 = blockIdx.x * EPB;

  if (t < EPB) { srcs[t] = ei[e0 + t]; lens_s[t] = lens[e0 + t]; }
  __syncthreads();
  {
    const float step = 5.f / 11.f;
    const float sq = 3.1622776601683795f;   // sqrt(10)
    for (int idx = t; idx < EPB * NBASIS; idx += 256) {
      int e = idx / NBASIS, k = idx % NBASIS;
      float d = (lens_s[e] - (float)(k + 1) * step) / step;
      embs[e][k] = (d > -1.f && d < 1.f) ? cosf(1.5707963267948966f * d) * sq : 0.f;
    }
  }
  __syncthreads();

  // phase 1: rh = silu(emb @ r1 + b1)
  {
    int e = t & 63;
    int kbase = t >> 6;   // 0..3
#pragma unroll
    for (int i = 0; i < 25; ++i) {
      int k = i * 4 + kbase;
      float s = b1l[k];
#pragma unroll
      for (int j = 0; j < NBASIS; ++j) s += embs[e][j] * r1l[j * RHID + k];
      rhT[k][e] = s / (1.f + expf(-s));
    }
  }
  __syncthreads();

  int tx = t & 15, ty = t >> 4;   // 4 edges (ty*4+i) x 4 cols (tx*4+j)
  for (int cb = 0; cb < 4; ++cb) {
    for (int idx = t; idx < RHID * 64; idx += 256) {
      int k = idx >> 6, c = idx & 63;
      r2s[k][c] = r2l[(size_t)k * HD + cb * 64 + c];
    }
    __syncthreads();
    float acc[4][4];
#pragma unroll
    for (int i = 0; i < 4; ++i)
#pragma unroll
      for (int j = 0; j < 4; ++j) acc[i][j] = 0.f;
    for (int k = 0; k < RHID; ++k) {
      float4 av = *(const float4*)&rhT[k][ty * 4];
      float4 bv = *(const float4*)&r2s[k][tx * 4];
      float a[4] = {av.x, av.y, av.z, av.w};
      float b[4] = {bv.x, bv.y, bv.z, bv.w};
#pragma unroll
      for (int i = 0; i < 4; ++i)
#pragma unroll
        for (int j = 0; j < 4; ++j) acc[i][j] += a[i] * b[j];
    }
#pragma unroll
    for (int i = 0; i < 4; ++i) {
      int e = ty * 4 + i;
      int src = srcs[e];
      f16x4 hv = *(const f16x4*)(h + (size_t)src * HD + cb * 64 + tx * 4);
      f16x4 o;
      o[0] = (f16)(acc[i][0] * (float)hv[0]);
      o[1] = (f16)(acc[i][1] * (float)hv[1]);
      o[2] = (f16)(acc[i][2] * (float)hv[2]);
      o[3] = (f16)(acc[i][3] * (float)hv[3]);
      *(f16x4*)(hs + (size_t)(e0 + e) * HD + cb * 64 + tx * 4) = o;
    }
    __syncthreads();
  }
}

// ---------------- gather: T[n, a*256+c] = sum_{e->n} sh[e,a]*hs[e,c], f16 ----------
#define NPB2 5
__global__ __launch_bounds__(256) void gather_T2_kernel(
    const int* __restrict__ rowptr, const int* __restrict__ eids,
    const f16* __restrict__ hs, const f16* __restrict__ sh,
    f16* __restrict__ T)
{
  int c = threadIdx.x;
  int n0 = blockIdx.x * NPB2;
  for (int n = n0; n < n0 + NPB2; ++n) {
    int beg = rowptr[n], end = rowptr[n + 1];
    float acc[NSH];
#pragma unroll
    for (int a = 0; a < NSH; ++a) acc[a] = 0.f;
    for (int j = beg; j < end; ++j) {
      int e = eids[j];
      f16x8 s8 = *(const f16x8*)(sh + (size_t)e * SHSTR);
      float s8v = (float)sh[(size_t)e * SHSTR + 8];
      float hv = (float)hs[(size_t)e * HD + c];
#pragma unroll
      for (int a = 0; a < 8; ++a) acc[a] += (float)s8[a] * hv;
      acc[8] += s8v * hv;
    }
    f16* Tn = T + (size_t)n * KTP + c;
#pragma unroll
    for (int a = 0; a < NSH; ++a) Tn[a * HD] = (f16)acc[a];
  }
}

// ---------------- MFMA GEMM: C = gelu(T@Bcat[:2304] + h@Bcat[2304:]), f16 in/out ----
#define GBM 64
#define GBN 128
__global__ __launch_bounds__(256) void gemm_mfma_kernel(
    const f16* __restrict__ A1,   // T [MPAD][2304]
    const f16* __restrict__ A2,   // h [MPAD][256]
    const f16* __restrict__ B,    // Bcat [256][2560] (n-major)
    f16* __restrict__ C, int M)
{
  __shared__ __align__(16) f16 As[4][GBM][8];   // [kchunk][m][8]  4 KB
  __shared__ __align__(16) f16 Bs[4][GBN][8];   // [kchunk][n][8]  8 KB
  int t = threadIdx.x;
  int lane = t & 63, w = t >> 6;
  int row0 = blockIdx.x * GBM;
  int n0 = blockIdx.y * GBN;
  f32x4 acc[2][4];
#pragma unroll
  for (int i = 0; i < 2; ++i)
#pragma unroll
    for (int j = 0; j < 4; ++j) acc[i][j] = (f32x4){0.f, 0.f, 0.f, 0.f};
  int mq = (w & 1) * 32, nq = (w >> 1) * 64;
  int cA = t >> 6, mA = t & 63;   // A staging: wave w stages chunk w, lane -> row

  for (int k0 = 0; k0 < KTOT; k0 += 32) {
    const f16* ga = (k0 < KTP)
        ? (A1 + (size_t)(row0 + mA) * KTP + k0 + cA * 8)
        : (A2 + (size_t)(row0 + mA) * HD + (k0 - KTP) + cA * 8);
    uint4 va = *(const uint4*)ga;
    *(uint4*)&As[cA][mA][0] = va;
#pragma unroll
    for (int u = 0; u < 2; ++u) {
      int idx = t + u * 256;
      int ch = idx >> 7, nn = idx & 127;
      uint4 vb = *(const uint4*)(B + (size_t)(n0 + nn) * KTOT + k0 + ch * 8);
      *(uint4*)&Bs[ch][nn][0] = vb;
    }
    __syncthreads();
    int q = lane >> 4, r = lane & 15;
    f16x8 af[2], bfr[4];
#pragma unroll
    for (int i = 0; i < 2; ++i) af[i] = *(const f16x8*)&As[q][mq + i * 16 + r][0];
#pragma unroll
    for (int j = 0; j < 4; ++j) bfr[j] = *(const f16x8*)&Bs[q][nq + j * 16 + r][0];
#pragma unroll
    for (int i = 0; i < 2; ++i)
#pragma unroll
      for (int j = 0; j < 4; ++j)
        acc[i][j] = __builtin_amdgcn_mfma_f32_16x16x32_f16(af[i], bfr[j], acc[i][j], 0, 0, 0);
    __syncthreads();
  }
  int q4 = (lane >> 4) * 4, cl = lane & 15;
#pragma unroll
  for (int i = 0; i < 2; ++i) {
#pragma unroll
    for (int rr = 0; rr < 4; ++rr) {
      int row = row0 + mq + i * 16 + q4 + rr;
      if (row >= M) continue;
#pragma unroll
      for (int j = 0; j < 4; ++j) {
        float v = gelu_tanh(acc[i][j][rr]);
        C[(size_t)row * HD + n0 + nq + j * 16 + cl] = (f16)v;
      }
    }
  }
}

// ---------------- fp32 GEMM (embed only): C_f16 = A@B ----------------
#define BM 64
#define BN 64
#define BK 16
__global__ __launch_bounds__(256) void gemm_f32_kernel(
    const float* __restrict__ A, const float* __restrict__ Bm, int K,
    f16* __restrict__ C, int M)
{
  __shared__ float As[BK][BM];
  __shared__ float Bs[BK][BN];
  int tid = threadIdx.x;
  int tx = tid & 15, ty = tid >> 4;
  int row0 = blockIdx.x * BM;
  int col0 = blockIdx.y * BN;
  float acc[4][4];
#pragma unroll
  for (int i = 0; i < 4; ++i)
#pragma unroll
    for (int j = 0; j < 4; ++j) acc[i][j] = 0.f;

  for (int k0 = 0; k0 < K; k0 += BK) {
    {
      int r = tid >> 2;
      int kq = (tid & 3) * 4;
      int gr = row0 + r;
#pragma unroll
      for (int j = 0; j < 4; ++j) {
        int gk = k0 + kq + j;
        As[kq + j][r] = (gr < M && gk < K) ? A[(size_t)gr * K + gk] : 0.f;
      }
    }
    {
#pragma unroll
      for (int t = 0; t < 4; ++t) {
        int idx = tid + t * 256;
        int kk = idx >> 6, nn = idx & 63;
        int gk = k0 + kk;
        Bs[kk][nn] = (gk < K) ? Bm[(size_t)gk * HD + col0 + nn] : 0.f;
      }
    }
    __syncthreads();
#pragma unroll
    for (int kk = 0; kk < BK; ++kk) {
      float a[4], b[4];
#pragma unroll
      for (int i = 0; i < 4; ++i) a[i] = As[kk][ty * 4 + i];
#pragma unroll
      for (int j = 0; j < 4; ++j) b[j] = Bs[kk][tx * 4 + j];
#pragma unroll
      for (int i = 0; i < 4; ++i)
#pragma unroll
        for (int j = 0; j < 4; ++j) acc[i][j] += a[i] * b[j];
    }
    __syncthreads();
  }
#pragma unroll
  for (int i = 0; i < 4; ++i) {
    int row = row0 + ty * 4 + i;
    if (row >= M) continue;
#pragma unroll
    for (int j = 0; j < 4; ++j)
      C[(size_t)row * HD + col0 + tx * 4 + j] = (f16)acc[i][j];
  }
}

// ---------------- node_out + graph sums ----------------
__global__ void node_out_kernel(const f16* __restrict__ h,
                                const float* __restrict__ Wout,
                                const int* __restrict__ batch,
                                float* __restrict__ sums,
                                float* __restrict__ cnts)
{
  int n = blockIdx.x * 4 + (threadIdx.x >> 6);
  int lane = threadIdx.x & 63;
  if (n >= NNODE) return;
  float s = 0.f;
#pragma unroll
  for (int t = 0; t < 4; ++t) {
    int c = lane + t * 64;
    s += (float)h[(size_t)n * HD + c] * Wout[c];
  }
#pragma unroll
  for (int off = 32; off > 0; off >>= 1) s += __shfl_down(s, off);
  if (lane == 0) {
    int g = batch[n];
    atomicAdd(&sums[g], s);
    atomicAdd(&cnts[g], 1.f);
  }
}

__global__ void finalize_kernel(const float* __restrict__ sums,
                                const float* __restrict__ cnts,
                                float* __restrict__ out)
{
  int g = threadIdx.x;
  if (g < NGRAPH) out[g] = sums[g] / fmaxf(cnts[g], 1.f);
}

// ---------------- host launch ----------------
extern "C" void kernel_launch(void* const* d_in, const int* in_sizes, int n_in,
                              void* d_out, int out_size, void* d_ws, size_t ws_size,
                              hipStream_t stream)
{
  (void)in_sizes; (void)n_in; (void)out_size;
  const float* x     = (const float*)d_in[0];
  const float* pos   = (const float*)d_in[1];
  const float* shift = (const float*)d_in[2];
  const float* lat   = (const float*)d_in[3];
  const float* Wemb  = (const float*)d_in[4];
  const float* r1    = (const float*)d_in[5];
  const float* b1    = (const float*)d_in[6];
  const float* r2    = (const float*)d_in[7];
  const float* Wtp   = (const float*)d_in[8];
  const float* Wself = (const float*)d_in[9];
  const float* Wskip = (const float*)d_in[10];
  const float* Wout  = (const float*)d_in[11];
  const int*   eidx  = (const int*)d_in[12];
  const int*   batch = (const int*)d_in[13];
  float* out = (float*)d_out;

  char* ws = (char*)d_ws;
  size_t off = 0;
  auto alloc = [&](size_t bytes) -> char* {
    char* p = ws + off;
    off += (bytes + 255) & ~(size_t)255;
    return p;
  };
  f16*   sh     = (f16*)alloc((size_t)NEDGE * SHSTR * 2);       //  7.68 MB
  float* lens   = (float*)alloc((size_t)NEDGE * 4);             //  0.96 MB
  f16*   hA     = (f16*)alloc((size_t)MPAD * HD * 2);           // 10.29 MB
  f16*   hB     = (f16*)alloc((size_t)MPAD * HD * 2);           // 10.29 MB
  f16*   T      = (f16*)alloc((size_t)MPAD * KTP * 2);          // 92.60 MB
  f16*   hs     = (f16*)alloc((size_t)NEDGE * HD * 2);          // 122.88 MB
  f16*   Bcat   = (f16*)alloc((size_t)HD * KTOT * 2);           //  1.31 MB
  int*   rowptr = (int*)alloc((size_t)(NNODE + 1) * 4);
  int*   deg    = (int*)alloc((size_t)NNODE * 4);
  int*   cursor = (int*)alloc((size_t)NNODE * 4);
  int*   eids   = (int*)alloc((size_t)NEDGE * 4);
  float* sums   = (float*)alloc((size_t)NGRAPH * 4);
  float* cnts   = (float*)alloc((size_t)NGRAPH * 4);
  if (off > ws_size) return;  // total ~247.2 MB; round-1 proved >= 249.96 MB available

  hipMemsetAsync(deg, 0, (size_t)NNODE * 4, stream);
  hipMemsetAsync(cursor, 0, (size_t)NNODE * 4, stream);
  hipMemsetAsync(sums, 0, (size_t)NGRAPH * 4, stream);
  hipMemsetAsync(cnts, 0, (size_t)NGRAPH * 4, stream);

  const int EB = (NEDGE + 255) / 256;
  edge_geom_kernel<<<EB, 256, 0, stream>>>(pos, shift, lat, eidx, batch, sh, lens);
  deg_hist_kernel<<<EB, 256, 0, stream>>>(eidx, deg);
  scan_kernel<<<1, 256, 0, stream>>>(deg, rowptr);
  fill_kernel<<<EB, 256, 0, stream>>>(eidx, rowptr, cursor, eids);

  // h0 = x @ W_embed  (fp32 in, f16 out)
  dim3 egrid((NNODE + BM - 1) / BM, HD / BN);
  gemm_f32_kernel<<<egrid, 256, 0, stream>>>(x, Wemb, DIN, hA, NNODE);

  f16* hcur = hA;
  f16* hnxt = hB;
  dim3 ggrid((NNODE + GBM - 1) / GBM, HD / GBN);   // (313, 2)
  for (int l = 0; l < NLAYER; ++l) {
    const float* r1l = r1 + (size_t)l * NBASIS * RHID;
    const float* b1l = b1 + (size_t)l * RHID;
    const float* r2l = r2 + (size_t)l * RHID * HD;
    const float* Wtp_l = Wtp + (size_t)l * NSH * HD * HD;
    const float* Wself_l = Wself + (size_t)l * HD * HD;
    const float* Wskip_l = Wskip + (size_t)l * HD * HD;

    wcat_kernel<<<KTOT, 256, 0, stream>>>(Wtp_l, Wself_l, Wskip_l, Bcat);
    hs_kernel<<<NEDGE / EPB, 256, 0, stream>>>(eidx, lens, hcur, r1l, b1l, r2l, hs);
    gather_T2_kernel<<<NNODE / NPB2, 256, 0, stream>>>(rowptr, eids, hs, sh, T);
    gemm_mfma_kernel<<<ggrid, 256, 0, stream>>>(T, hcur, Bcat, hnxt, NNODE);
    f16* tmp = hcur; hcur = hnxt; hnxt = tmp;
  }

  node_out_kernel<<<NNODE / 4, 256, 0, stream>>>(hcur, Wout, batch, sums, cnts);
  finalize_kernel<<<1, 256, 0, stream>>>(sums, cnts, out);
}

// Round 4
// 1207.753 us; speedup vs baseline: 3.7396x; 1.3092x over previous
//
#include <hip/hip_runtime.h>
#include <hip/hip_bf16.h>
#include <cstddef>
#include <cstdint>

#define NNODE  20000
#define MPAD   20096        // 157*128 padding for GEMM row tiles
#define NEDGE  240000
#define NGRAPH 200
#define DIN    118
#define HD     256
#define NBASIS 10
#define RHID   100
#define NLAYER 3
#define NSH    9
#define SHSTR  16           // sh row stride in f16 elements (32 B)
#define KTP    (NSH * HD)   // 2304
#define KTOT   (KTP + HD)   // 2560
#define KR2    128          // padded radial K (100 -> 128)

typedef _Float16 f16;
typedef _Float16 f16x4 __attribute__((ext_vector_type(4)));
typedef _Float16 f16x8 __attribute__((ext_vector_type(8)));
typedef float    f32x4 __attribute__((ext_vector_type(4)));

__device__ __forceinline__ float gelu_tanh(float v) {
  float v3 = v * v * v;
  return 0.5f * v * (1.f + tanhf(0.7978845608028654f * (v + 0.044715f * v3)));
}

// ---------------- edge geometry: sh[E,16] f16 (9 used), lens[E] ----------------
__global__ void edge_geom_kernel(const float* __restrict__ pos,
                                 const float* __restrict__ shift,
                                 const float* __restrict__ lat,
                                 const int* __restrict__ ei,
                                 const int* __restrict__ batch,
                                 f16* __restrict__ sh,
                                 float* __restrict__ lens)
{
  int e = blockIdx.x * 256 + threadIdx.x;
  if (e >= NEDGE) return;
  int src = ei[e];
  int dst = ei[NEDGE + e];
  int b = batch[src];
  const float* L = lat + (size_t)b * 9;
  float s0 = shift[e * 3 + 0], s1 = shift[e * 3 + 1], s2 = shift[e * 3 + 2];
  float ev[3];
#pragma unroll
  for (int j = 0; j < 3; ++j)
    ev[j] = pos[dst * 3 + j] - pos[src * 3 + j] + s0 * L[j] + s1 * L[3 + j] + s2 * L[6 + j];
  float len = sqrtf(ev[0] * ev[0] + ev[1] * ev[1] + ev[2] * ev[2]);
  float inv = 1.f / (len + 1e-12f);
  float x = ev[0] * inv, y = ev[1] * inv, z = ev[2] * inv;
  const float c1 = 1.7320508075688772f;   // sqrt(3)
  const float c2 = 3.872983346207417f;    // sqrt(15)
  f16* she = sh + (size_t)e * SHSTR;
  she[0] = (f16)1.f;
  she[1] = (f16)(c1 * x);
  she[2] = (f16)(c1 * y);
  she[3] = (f16)(c1 * z);
  she[4] = (f16)(c2 * x * y);
  she[5] = (f16)(c2 * y * z);
  she[6] = (f16)(1.1180339887498949f * (3.f * z * z - 1.f));  // sqrt(5)/2
  she[7] = (f16)(c2 * x * z);
  she[8] = (f16)(1.9364916731037085f * (x * x - y * y));      // sqrt(15)/2
  lens[e] = len;
}

// ---------------- CSR build ----------------
__global__ void deg_hist_kernel(const int* __restrict__ ei, int* __restrict__ deg)
{
  int e = blockIdx.x * 256 + threadIdx.x;
  if (e >= NEDGE) return;
  atomicAdd(&deg[ei[NEDGE + e]], 1);
}

__global__ void scan_kernel(const int* __restrict__ deg, int* __restrict__ rowptr)
{
  __shared__ int part[256];
  int t = threadIdx.x;
  const int chunk = (NNODE + 255) / 256;
  int start = t * chunk;
  int end = min(start + chunk, NNODE);
  int s = 0;
  for (int i = start; i < end; ++i) s += deg[i];
  part[t] = s;
  __syncthreads();
  for (int off = 1; off < 256; off <<= 1) {
    int v = (t >= off) ? part[t - off] : 0;
    __syncthreads();
    part[t] += v;
    __syncthreads();
  }
  int run = (t == 0) ? 0 : part[t - 1];
  for (int i = start; i < end; ++i) { rowptr[i] = run; run += deg[i]; }
  if (t == 255) rowptr[NNODE] = run;
}

__global__ void fill_kernel(const int* __restrict__ ei,
                            const int* __restrict__ rowptr,
                            int* __restrict__ cursor,
                            int* __restrict__ eids)
{
  int e = blockIdx.x * 256 + threadIdx.x;
  if (e >= NEDGE) return;
  int dst = ei[NEDGE + e];
  int p = atomicAdd(&cursor[dst], 1);
  eids[rowptr[dst] + p] = e;
}

// ------- Bcat[n][k] f16 (n-major): k<2304: (Wtp_flat@Wself)*inv_sqrt_deg ; else Wskip -------
__global__ void wcat_kernel(const float* __restrict__ Wtp_l,
                            const float* __restrict__ Wself_l,
                            const float* __restrict__ Wskip_l,
                            f16* __restrict__ Bcat)
{
  int p = blockIdx.x;       // 0..2559 (k index)
  int j = threadIdx.x;      // 0..255  (n index)
  float s;
  if (p < KTP) {
    const float* wrow = Wtp_l + (size_t)p * HD;
    s = 0.f;
    for (int m = 0; m < HD; ++m) s += wrow[m] * Wself_l[m * HD + j];
    s *= 0.28867513459481287f;  // 1/sqrt(12)
  } else {
    s = Wskip_l[(size_t)(p - KTP) * HD + j];
  }
  Bcat[(size_t)j * KTOT + p] = (f16)s;
}

// ---------------- r2h[n][k] f16 n-major, k padded to 128 ----------------
__global__ void r2conv_kernel(const float* __restrict__ r2l, f16* __restrict__ r2h)
{
  int n = blockIdx.x;       // 0..255
  int k = threadIdx.x;      // 0..127
  r2h[(size_t)n * KR2 + k] = (k < RHID) ? (f16)r2l[(size_t)k * HD + n] : (f16)0.f;
}

// ------- hs[e,c] = h[src_e,c] * (silu(emb@r1+b1)@r2)[e,c], MFMA, f16 out -------
#define EPB 64
#define RHSTR 136   // rhA row stride in f16 (272 B = 17*16B: aligned, 8-group banks)
__global__ __launch_bounds__(256) void hs_mfma_kernel(
    const int* __restrict__ ei, const float* __restrict__ lens,
    const f16* __restrict__ h,
    const float* __restrict__ r1l, const float* __restrict__ b1l,
    const f16* __restrict__ r2h, f16* __restrict__ hs)
{
  __shared__ float embs[EPB][11];
  __shared__ float r1s[NBASIS * RHID];
  __shared__ float b1s[RHID];
  __shared__ int   srcs[EPB];
  __shared__ float lens_s[EPB];
  __shared__ __align__(16) f16 rhA[EPB][RHSTR];
  int t = threadIdx.x;
  int lane = t & 63, w = t >> 6;
  int e0 = blockIdx.x * EPB;

  if (t < EPB) { srcs[t] = ei[e0 + t]; lens_s[t] = lens[e0 + t]; }
  for (int idx = t; idx < NBASIS * RHID; idx += 256) r1s[idx] = r1l[idx];
  if (t < RHID) b1s[t] = b1l[t];
  __syncthreads();
  {
    const float step = 5.f / 11.f;
    const float sq = 3.1622776601683795f;   // sqrt(10)
    for (int idx = t; idx < EPB * NBASIS; idx += 256) {
      int e = idx / NBASIS, k = idx % NBASIS;
      float d = (lens_s[e] - (float)(k + 1) * step) / step;
      embs[e][k] = (d > -1.f && d < 1.f) ? cosf(1.5707963267948966f * d) * sq : 0.f;
    }
  }
  __syncthreads();

  // phase 1: rhA[e][k] = silu(emb@r1+b1), f16, k padded to 128
#pragma unroll
  for (int i = 0; i < 4; ++i) {
    int e = lane;
    int g = i * 4 + w;            // 16-byte chunk index (8 f16)
    f16x8 v;
#pragma unroll
    for (int kk = 0; kk < 8; ++kk) {
      int k = g * 8 + kk;
      float s = 0.f;
      if (k < RHID) {
        s = b1s[k];
#pragma unroll
        for (int j = 0; j < NBASIS; ++j) s += embs[e][j] * r1s[j * RHID + k];
        s = s / (1.f + expf(-s));
      }
      v[kk] = (f16)s;
    }
    *(f16x8*)&rhA[e][g * 8] = v;
  }
  __syncthreads();

  // phase 2: MFMA rh[64,128] @ r2h^T[128,256]; wave w -> n block w*64
  int r = lane & 15, q = lane >> 4;
  int n0w = w * 64;
  f16x8 bf[4][4];   // [ntile][kstep]
#pragma unroll
  for (int j = 0; j < 4; ++j)
#pragma unroll
    for (int ks = 0; ks < 4; ++ks)
      bf[j][ks] = *(const f16x8*)(r2h + (size_t)(n0w + j * 16 + r) * KR2 + ks * 32 + q * 8);

  f32x4 acc[4][4];  // [mtile][ntile]
#pragma unroll
  for (int i = 0; i < 4; ++i)
#pragma unroll
    for (int j = 0; j < 4; ++j) acc[i][j] = (f32x4){0.f, 0.f, 0.f, 0.f};

#pragma unroll
  for (int ks = 0; ks < 4; ++ks) {
    f16x8 af[4];
#pragma unroll
    for (int i = 0; i < 4; ++i)
      af[i] = *(const f16x8*)&rhA[i * 16 + r][ks * 32 + q * 8];
#pragma unroll
    for (int i = 0; i < 4; ++i)
#pragma unroll
      for (int j = 0; j < 4; ++j)
        acc[i][j] = __builtin_amdgcn_mfma_f32_16x16x32_f16(af[i], bf[j][ks], acc[i][j], 0, 0, 0);
  }

  // epilogue: multiply by h[src] and store
#pragma unroll
  for (int i = 0; i < 4; ++i) {
#pragma unroll
    for (int rr = 0; rr < 4; ++rr) {
      int m = i * 16 + q * 4 + rr;
      int src = srcs[m];
#pragma unroll
      for (int j = 0; j < 4; ++j) {
        int col = n0w + j * 16 + r;
        float hv = (float)h[(size_t)src * HD + col];
        hs[(size_t)(e0 + m) * HD + col] = (f16)(acc[i][j][rr] * hv);
      }
    }
  }
}

// ---------------- gather: T[n, a*256+c] = sum_{e->n} sh[e,a]*hs[e,c], f16 ----------
#define NPB2 5
__global__ __launch_bounds__(256) void gather_T2_kernel(
    const int* __restrict__ rowptr, const int* __restrict__ eids,
    const f16* __restrict__ hs, const f16* __restrict__ sh,
    f16* __restrict__ T)
{
  int c = threadIdx.x;
  int n0 = blockIdx.x * NPB2;
  for (int n = n0; n < n0 + NPB2; ++n) {
    int beg = rowptr[n], end = rowptr[n + 1];
    float acc[NSH];
#pragma unroll
    for (int a = 0; a < NSH; ++a) acc[a] = 0.f;
    for (int j = beg; j < end; ++j) {
      int e = eids[j];
      f16x8 s8 = *(const f16x8*)(sh + (size_t)e * SHSTR);
      float s8v = (float)sh[(size_t)e * SHSTR + 8];
      float hv = (float)hs[(size_t)e * HD + c];
#pragma unroll
      for (int a = 0; a < 8; ++a) acc[a] += (float)s8[a] * hv;
      acc[8] += s8v * hv;
    }
    f16* Tn = T + (size_t)n * KTP + c;
#pragma unroll
    for (int a = 0; a < NSH; ++a) Tn[a * HD] = (f16)acc[a];
  }
}

// ---------------- MFMA GEMM: C = gelu(T@Bcat[:2304] + h@Bcat[2304:]), f16 in/out ----
#define GBM 64
#define GBN 128
__global__ __launch_bounds__(256) void gemm_mfma_kernel(
    const f16* __restrict__ A1,   // T [MPAD][2304]
    const f16* __restrict__ A2,   // h [MPAD][256]
    const f16* __restrict__ B,    // Bcat [256][2560] (n-major)
    f16* __restrict__ C, int M)
{
  __shared__ __align__(16) f16 As[4][GBM][8];   // [kchunk][m][8]  4 KB
  __shared__ __align__(16) f16 Bs[4][GBN][8];   // [kchunk][n][8]  8 KB
  int t = threadIdx.x;
  int lane = t & 63, w = t >> 6;
  int row0 = blockIdx.x * GBM;
  int n0 = blockIdx.y * GBN;
  f32x4 acc[2][4];
#pragma unroll
  for (int i = 0; i < 2; ++i)
#pragma unroll
    for (int j = 0; j < 4; ++j) acc[i][j] = (f32x4){0.f, 0.f, 0.f, 0.f};
  int mq = (w & 1) * 32, nq = (w >> 1) * 64;
  int cA = t >> 6, mA = t & 63;   // A staging: wave w stages chunk w, lane -> row

  for (int k0 = 0; k0 < KTOT; k0 += 32) {
    const f16* ga = (k0 < KTP)
        ? (A1 + (size_t)(row0 + mA) * KTP + k0 + cA * 8)
        : (A2 + (size_t)(row0 + mA) * HD + (k0 - KTP) + cA * 8);
    uint4 va = *(const uint4*)ga;
    *(uint4*)&As[cA][mA][0] = va;
#pragma unroll
    for (int u = 0; u < 2; ++u) {
      int idx = t + u * 256;
      int ch = idx >> 7, nn = idx & 127;
      uint4 vb = *(const uint4*)(B + (size_t)(n0 + nn) * KTOT + k0 + ch * 8);
      *(uint4*)&Bs[ch][nn][0] = vb;
    }
    __syncthreads();
    int q = lane >> 4, r = lane & 15;
    f16x8 af[2], bfr[4];
#pragma unroll
    for (int i = 0; i < 2; ++i) af[i] = *(const f16x8*)&As[q][mq + i * 16 + r][0];
#pragma unroll
    for (int j = 0; j < 4; ++j) bfr[j] = *(const f16x8*)&Bs[q][nq + j * 16 + r][0];
#pragma unroll
    for (int i = 0; i < 2; ++i)
#pragma unroll
      for (int j = 0; j < 4; ++j)
        acc[i][j] = __builtin_amdgcn_mfma_f32_16x16x32_f16(af[i], bfr[j], acc[i][j], 0, 0, 0);
    __syncthreads();
  }
  int q4 = (lane >> 4) * 4, cl = lane & 15;
#pragma unroll
  for (int i = 0; i < 2; ++i) {
#pragma unroll
    for (int rr = 0; rr < 4; ++rr) {
      int row = row0 + mq + i * 16 + q4 + rr;
      if (row >= M) continue;
#pragma unroll
      for (int j = 0; j < 4; ++j) {
        float v = gelu_tanh(acc[i][j][rr]);
        C[(size_t)row * HD + n0 + nq + j * 16 + cl] = (f16)v;
      }
    }
  }
}

// ---------------- fp32 GEMM (embed only): C_f16 = A@B ----------------
#define BM 64
#define BN 64
#define BK 16
__global__ __launch_bounds__(256) void gemm_f32_kernel(
    const float* __restrict__ A, const float* __restrict__ Bm, int K,
    f16* __restrict__ C, int M)
{
  __shared__ float As[BK][BM];
  __shared__ float Bs[BK][BN];
  int tid = threadIdx.x;
  int tx = tid & 15, ty = tid >> 4;
  int row0 = blockIdx.x * BM;
  int col0 = blockIdx.y * BN;
  float acc[4][4];
#pragma unroll
  for (int i = 0; i < 4; ++i)
#pragma unroll
    for (int j = 0; j < 4; ++j) acc[i][j] = 0.f;

  for (int k0 = 0; k0 < K; k0 += BK) {
    {
      int r = tid >> 2;
      int kq = (tid & 3) * 4;
      int gr = row0 + r;
#pragma unroll
      for (int j = 0; j < 4; ++j) {
        int gk = k0 + kq + j;
        As[kq + j][r] = (gr < M && gk < K) ? A[(size_t)gr * K + gk] : 0.f;
      }
    }
    {
#pragma unroll
      for (int t = 0; t < 4; ++t) {
        int idx = tid + t * 256;
        int kk = idx >> 6, nn = idx & 63;
        int gk = k0 + kk;
        Bs[kk][nn] = (gk < K) ? Bm[(size_t)gk * HD + col0 + nn] : 0.f;
      }
    }
    __syncthreads();
#pragma unroll
    for (int kk = 0; kk < BK; ++kk) {
      float a[4], b[4];
#pragma unroll
      for (int i = 0; i < 4; ++i) a[i] = As[kk][ty * 4 + i];
#pragma unroll
      for (int j = 0; j < 4; ++j) b[j] = Bs[kk][tx * 4 + j];
#pragma unroll
      for (int i = 0; i < 4; ++i)
#pragma unroll
        for (int j = 0; j < 4; ++j) acc[i][j] += a[i] * b[j];
    }
    __syncthreads();
  }
#pragma unroll
  for (int i = 0; i < 4; ++i) {
    int row = row0 + ty * 4 + i;
    if (row >= M) continue;
#pragma unroll
    for (int j = 0; j < 4; ++j)
      C[(size_t)row * HD + col0 + tx * 4 + j] = (f16)acc[i][j];
  }
}

// ---------------- node_out + graph sums ----------------
__global__ void node_out_kernel(const f16* __restrict__ h,
                                const float* __restrict__ Wout,
                                const int* __restrict__ batch,
                                float* __restrict__ sums,
                                float* __restrict__ cnts)
{
  int n = blockIdx.x * 4 + (threadIdx.x >> 6);
  int lane = threadIdx.x & 63;
  if (n >= NNODE) return;
  float s = 0.f;
#pragma unroll
  for (int t = 0; t < 4; ++t) {
    int c = lane + t * 64;
    s += (float)h[(size_t)n * HD + c] * Wout[c];
  }
#pragma unroll
  for (int off = 32; off > 0; off >>= 1) s += __shfl_down(s, off);
  if (lane == 0) {
    int g = batch[n];
    atomicAdd(&sums[g], s);
    atomicAdd(&cnts[g], 1.f);
  }
}

__global__ void finalize_kernel(const float* __restrict__ sums,
                                const float* __restrict__ cnts,
                                float* __restrict__ out)
{
  int g = threadIdx.x;
  if (g < NGRAPH) out[g] = sums[g] / fmaxf(cnts[g], 1.f);
}

// ---------------- host launch ----------------
extern "C" void kernel_launch(void* const* d_in, const int* in_sizes, int n_in,
                              void* d_out, int out_size, void* d_ws, size_t ws_size,
                              hipStream_t stream)
{
  (void)in_sizes; (void)n_in; (void)out_size;
  const float* x     = (const float*)d_in[0];
  const float* pos   = (const float*)d_in[1];
  const float* shift = (const float*)d_in[2];
  const float* lat   = (const float*)d_in[3];
  const float* Wemb  = (const float*)d_in[4];
  const float* r1    = (const float*)d_in[5];
  const float* b1    = (const float*)d_in[6];
  const float* r2    = (const float*)d_in[7];
  const float* Wtp   = (const float*)d_in[8];
  const float* Wself = (const float*)d_in[9];
  const float* Wskip = (const float*)d_in[10];
  const float* Wout  = (const float*)d_in[11];
  const int*   eidx  = (const int*)d_in[12];
  const int*   batch = (const int*)d_in[13];
  float* out = (float*)d_out;

  char* ws = (char*)d_ws;
  size_t off = 0;
  auto alloc = [&](size_t bytes) -> char* {
    char* p = ws + off;
    off += (bytes + 255) & ~(size_t)255;
    return p;
  };
  f16*   sh     = (f16*)alloc((size_t)NEDGE * SHSTR * 2);       //  7.68 MB
  float* lens   = (float*)alloc((size_t)NEDGE * 4);             //  0.96 MB
  f16*   hA     = (f16*)alloc((size_t)MPAD * HD * 2);           // 10.29 MB
  f16*   hB     = (f16*)alloc((size_t)MPAD * HD * 2);           // 10.29 MB
  f16*   T      = (f16*)alloc((size_t)MPAD * KTP * 2);          // 92.60 MB
  f16*   hs     = (f16*)alloc((size_t)NEDGE * HD * 2);          // 122.88 MB
  f16*   Bcat   = (f16*)alloc((size_t)HD * KTOT * 2);           //  1.31 MB
  f16*   r2h    = (f16*)alloc((size_t)HD * KR2 * 2);            //  64 KB
  int*   rowptr = (int*)alloc((size_t)(NNODE + 1) * 4);
  int*   deg    = (int*)alloc((size_t)NNODE * 4);
  int*   cursor = (int*)alloc((size_t)NNODE * 4);
  int*   eids   = (int*)alloc((size_t)NEDGE * 4);
  float* sums   = (float*)alloc((size_t)NGRAPH * 4);
  float* cnts   = (float*)alloc((size_t)NGRAPH * 4);
  if (off > ws_size) return;  // total ~247.3 MB; round-1 proved >= 249.96 MB available

  hipMemsetAsync(deg, 0, (size_t)NNODE * 4, stream);
  hipMemsetAsync(cursor, 0, (size_t)NNODE * 4, stream);
  hipMemsetAsync(sums, 0, (size_t)NGRAPH * 4, stream);
  hipMemsetAsync(cnts, 0, (size_t)NGRAPH * 4, stream);

  const int EB = (NEDGE + 255) / 256;
  edge_geom_kernel<<<EB, 256, 0, stream>>>(pos, shift, lat, eidx, batch, sh, lens);
  deg_hist_kernel<<<EB, 256, 0, stream>>>(eidx, deg);
  scan_kernel<<<1, 256, 0, stream>>>(deg, rowptr);
  fill_kernel<<<EB, 256, 0, stream>>>(eidx, rowptr, cursor, eids);

  // h0 = x @ W_embed  (fp32 in, f16 out)
  dim3 egrid((NNODE + BM - 1) / BM, HD / BN);
  gemm_f32_kernel<<<egrid, 256, 0, stream>>>(x, Wemb, DIN, hA, NNODE);

  f16* hcur = hA;
  f16* hnxt = hB;
  dim3 ggrid((NNODE + GBM - 1) / GBM, HD / GBN);   // (313, 2)
  for (int l = 0; l < NLAYER; ++l) {
    const float* r1l = r1 + (size_t)l * NBASIS * RHID;
    const float* b1l = b1 + (size_t)l * RHID;
    const float* r2l = r2 + (size_t)l * RHID * HD;
    const float* Wtp_l = Wtp + (size_t)l * NSH * HD * HD;
    const float* Wself_l = Wself + (size_t)l * HD * HD;
    const float* Wskip_l = Wskip + (size_t)l * HD * HD;

    wcat_kernel<<<KTOT, 256, 0, stream>>>(Wtp_l, Wself_l, Wskip_l, Bcat);
    r2conv_kernel<<<HD, KR2, 0, stream>>>(r2l, r2h);
    hs_mfma_kernel<<<NEDGE / EPB, 256, 0, stream>>>(eidx, lens, hcur, r1l, b1l, r2h, hs);
    gather_T2_kernel<<<NNODE / NPB2, 256, 0, stream>>>(rowptr, eids, hs, sh, T);
    gemm_mfma_kernel<<<ggrid, 256, 0, stream>>>(T, hcur, Bcat, hnxt, NNODE);
    f16* tmp = hcur; hcur = hnxt; hnxt = tmp;
  }

  node_out_kernel<<<NNODE / 4, 256, 0, stream>>>(hcur, Wout, batch, sums, cnts);
  finalize_kernel<<<1, 256, 0, stream>>>(sums, cnts, out);
}